// Round 8
// baseline (152.077 us; speedup 1.0000x reference)
//
#include <hip/hip_runtime.h>

#define KLAB 32
#define FDIM 32
#define NPIX (512 * 512)
#define BATCH 8
#define EPSF 1e-12f

typedef __attribute__((ext_vector_type(8))) short bf16x8;
typedef __attribute__((ext_vector_type(4))) short bf16x4;
typedef __attribute__((ext_vector_type(4))) float f32x4;

__device__ __forceinline__ short f2bf(float f) {
    unsigned u = __builtin_bit_cast(unsigned, f);
    unsigned r = (u + 0x7FFFu + ((u >> 16) & 1u)) >> 16;   // RNE
    return (short)r;
}

__device__ __forceinline__ float bf2f(short s) {
    return __builtin_bit_cast(float, (unsigned)((unsigned short)s) << 16);
}

// Pass 1: LDS-staged MFMA one-hot GEMM. 512-thread blocks, 512-px tiles
// (half the barriers of the 256-px version), double-buffered swizzled LDS,
// stash-stores deferred one iteration so their drain has a full tile of slack.
__global__ __launch_bounds__(512, 4) void k_msums(
    const float* __restrict__ x, const int* __restrict__ lab,
    float* __restrict__ g_sums, float* __restrict__ g_cnt,
    short* __restrict__ xbf)
{
    __shared__ __align__(16) short alds[2][32 * 512];   // 2 x 32 KB bf16 tile
    __shared__ int lablds[2][512];

    const int tid = threadIdx.x;
    const int b = blockIdx.y;
    const int cx = blockIdx.x;                 // 0..63
    const int w = tid >> 6, l = tid & 63;      // 8 waves
    const int row = l & 15, grp = l >> 4;
    const size_t xb = (size_t)b * FDIM * NPIX;
    const size_t lb = (size_t)b * NPIX;
    const int bp0 = cx * 4096;                 // 4096 px/block, 8 tiles x 512

    const float* xw = x + xb + (size_t)(w * 4) * NPIX;   // wave's 4 staging rows
    short* xbw = xbf + xb + (size_t)(w * 4) * NPIX;

    f32x4 acc00{}, acc01{}, acc10{}, acc11{}, accC0{}, accC1{};
    bf16x8 ones;
#pragma unroll
    for (int j = 0; j < 8; ++j) ones[j] = (short)0x3F80;

    f32x4 sv[8];        // staged rows: [r][j], r=0..3, j=0..1 (static idx)
    bf16x4 st[8];       // converted stash, stored one iteration later
    int slab;

    // ---- prologue: stage tile 0 into buf 0, keep st for deferred store ----
    {
        const int sp = bp0;
#pragma unroll
        for (int r = 0; r < 4; ++r)
#pragma unroll
            for (int j = 0; j < 2; ++j)
                sv[r * 2 + j] = *reinterpret_cast<const f32x4*>(
                    xw + (size_t)r * NPIX + sp + j * 256 + l * 4);
        slab = lab[lb + sp + tid];
#pragma unroll
        for (int r = 0; r < 4; ++r)
#pragma unroll
            for (int j = 0; j < 2; ++j) {
                const f32x4 v = sv[r * 2 + j];
                bf16x4 c;
                c[0]=f2bf(v.x); c[1]=f2bf(v.y); c[2]=f2bf(v.z); c[3]=f2bf(v.w);
                st[r * 2 + j] = c;
                const int f = w * 4 + r;
                *reinterpret_cast<bf16x4*>((char*)&alds[0][0] +
                    ((f * 1024 + j * 512 + l * 8) ^ ((f & 7) << 4))) = c;
            }
        lablds[0][tid] = slab;
    }
    __syncthreads();

#pragma unroll 1
    for (int t = 0; t < 8; ++t) {
        const int cb = t & 1, nb = cb ^ 1;

        // 1. deferred global stash-store for tile t (full iteration of slack)
        {
            const int sp = bp0 + t * 512;
#pragma unroll
            for (int r = 0; r < 4; ++r)
#pragma unroll
                for (int j = 0; j < 2; ++j)
                    *reinterpret_cast<bf16x4*>(
                        xbw + (size_t)r * NPIX + sp + j * 256 + l * 4) = st[r * 2 + j];
        }

        // 2. issue-early: next tile's coalesced loads
        if (t + 1 < 8) {
            const int sp = bp0 + (t + 1) * 512;
#pragma unroll
            for (int r = 0; r < 4; ++r)
#pragma unroll
                for (int j = 0; j < 2; ++j)
                    sv[r * 2 + j] = *reinterpret_cast<const f32x4*>(
                        xw + (size_t)r * NPIX + sp + j * 256 + l * 4);
            slab = lab[lb + sp + tid];
        }

        // 3. compute current tile: wave owns k-steps 2w, 2w+1 (32 px each)
#pragma unroll
        for (int kq = 0; kq < 2; ++kq) {
            const int kk = 2 * w + kq;             // 0..15
            const int cbyte = (kk * 32 + grp * 8) * 2;
            const int swz = (row & 7) << 4;        // (row+16)&7 == row&7
            const bf16x8 a0 = *reinterpret_cast<const bf16x8*>(
                (char*)&alds[cb][0] + ((row * 1024 + cbyte) ^ swz));
            const bf16x8 a1 = *reinterpret_cast<const bf16x8*>(
                (char*)&alds[cb][0] + (((row + 16) * 1024 + cbyte) ^ swz));
            const int base = kk * 32 + grp * 8;
            const int4 la = *reinterpret_cast<const int4*>(&lablds[cb][base]);
            const int4 lc = *reinterpret_cast<const int4*>(&lablds[cb][base + 4]);
            bf16x8 b0, b1;
            const int lj[8] = {la.x, la.y, la.z, la.w, lc.x, lc.y, lc.z, lc.w};
#pragma unroll
            for (int j = 0; j < 8; ++j) {
                b0[j] = (lj[j] == row)      ? (short)0x3F80 : (short)0;
                b1[j] = (lj[j] == row + 16) ? (short)0x3F80 : (short)0;
            }
            acc00 = __builtin_amdgcn_mfma_f32_16x16x32_bf16(a0, b0, acc00, 0, 0, 0);
            acc10 = __builtin_amdgcn_mfma_f32_16x16x32_bf16(a1, b0, acc10, 0, 0, 0);
            acc01 = __builtin_amdgcn_mfma_f32_16x16x32_bf16(a0, b1, acc01, 0, 0, 0);
            acc11 = __builtin_amdgcn_mfma_f32_16x16x32_bf16(a1, b1, acc11, 0, 0, 0);
            accC0 = __builtin_amdgcn_mfma_f32_16x16x32_bf16(ones, b0, accC0, 0, 0, 0);
            accC1 = __builtin_amdgcn_mfma_f32_16x16x32_bf16(ones, b1, accC1, 0, 0, 0);
        }

        // 4. write-late: convert + LDS next buffer (global store deferred)
        if (t + 1 < 8) {
#pragma unroll
            for (int r = 0; r < 4; ++r)
#pragma unroll
                for (int j = 0; j < 2; ++j) {
                    const f32x4 v = sv[r * 2 + j];
                    bf16x4 c;
                    c[0]=f2bf(v.x); c[1]=f2bf(v.y); c[2]=f2bf(v.z); c[3]=f2bf(v.w);
                    st[r * 2 + j] = c;
                    const int f = w * 4 + r;
                    *reinterpret_cast<bf16x4*>((char*)&alds[nb][0] +
                        ((f * 1024 + j * 512 + l * 8) ^ ((f & 7) << 4))) = c;
                }
            lablds[nb][tid] = slab;
        }
        __syncthreads();
    }

    // epilogue: block reduce over 8 waves (s_red aliases alds[0], 32 KB)
    float* s_red = reinterpret_cast<float*>(&alds[0][0]);   // [8][1024]
#pragma unroll
    for (int i = 0; i < 4; ++i) {
        // C layout: col = lane&15, row = (lane>>4)*4 + i  [measured m89]
        const int fr = grp * 4 + i;
        s_red[w * 1024 + (fr)      * KLAB + row]      = acc00[i];
        s_red[w * 1024 + (fr)      * KLAB + row + 16] = acc01[i];
        s_red[w * 1024 + (fr + 16) * KLAB + row]      = acc10[i];
        s_red[w * 1024 + (fr + 16) * KLAB + row + 16] = acc11[i];
    }
    __syncthreads();
    float* gs = g_sums + (size_t)b * FDIM * KLAB;
    for (int i = tid; i < FDIM * KLAB; i += 512) {
        float s = 0.f;
#pragma unroll
        for (int ww = 0; ww < 8; ++ww) s += s_red[ww * 1024 + i];
        atomicAdd(&gs[i], s);
    }
    if (l < 16) {   // counts: row 0 of ones-GEMM, each wave its own share
        atomicAdd(&g_cnt[b * KLAB + l],      accC0[0]);
        atomicAdd(&g_cnt[b * KLAB + l + 16], accC1[0]);
    }
}

// Pass 2: per-pixel ||mu_label - x|| from the bf16 stash. 4 px/thread,
// depth-4 prefetch (static slot indices), 8 blocks/CU.
__global__ __launch_bounds__(256) void k_var(
    const short* __restrict__ xbf, const int* __restrict__ lab,
    const float* __restrict__ g_sums, const float* __restrict__ g_cnt,
    float* __restrict__ g_vsum)
{
    __shared__ float mu_s[FDIM][KLAB];
    __shared__ float vloc[KLAB];
    const int tid = threadIdx.x;
    const int b = blockIdx.y;
    for (int i = tid; i < FDIM * KLAB; i += 256) {
        const int k = i & (KLAB - 1);
        (&mu_s[0][0])[i] = g_sums[(size_t)b * FDIM * KLAB + i] / fmaxf(g_cnt[b * KLAB + k], 1.f);
    }
    if (tid < KLAB) vloc[tid] = 0.f;
    __syncthreads();

    const int n0 = blockIdx.x * 1024 + tid * 4;      // grid(256,B): 4 px/thread
    const size_t lb = (size_t)b * NPIX;
    const int4 l4 = *reinterpret_cast<const int4*>(&lab[lb + n0]);
    const int k0 = l4.x & 31, k1 = l4.y & 31, k2 = l4.z & 31, k3 = l4.w & 31;
    const short* xp = xbf + (size_t)b * FDIM * NPIX + n0;

    bf16x4 sl[4];
#pragma unroll
    for (int f = 0; f < 4; ++f)
        sl[f] = *reinterpret_cast<const bf16x4*>(xp + (size_t)f * NPIX);

    float d0 = 0.f, d1 = 0.f, d2 = 0.f, d3 = 0.f;
#pragma unroll
    for (int f = 0; f < FDIM; ++f) {                 // full unroll: f&3 static
        const bf16x4 cur = sl[f & 3];
        if (f + 4 < FDIM)
            sl[f & 3] = *reinterpret_cast<const bf16x4*>(xp + (size_t)(f + 4) * NPIX);
        const float* mf = &mu_s[f][0];
        float t;
        t = bf2f(cur[0]) - mf[k0]; d0 += t * t;
        t = bf2f(cur[1]) - mf[k1]; d1 += t * t;
        t = bf2f(cur[2]) - mf[k2]; d2 += t * t;
        t = bf2f(cur[3]) - mf[k3]; d3 += t * t;
    }
    float h;
    h = fmaxf(sqrtf(d0 + EPSF) - 0.5f, 0.f); atomicAdd(&vloc[k0], h * h);
    h = fmaxf(sqrtf(d1 + EPSF) - 0.5f, 0.f); atomicAdd(&vloc[k1], h * h);
    h = fmaxf(sqrtf(d2 + EPSF) - 0.5f, 0.f); atomicAdd(&vloc[k2], h * h);
    h = fmaxf(sqrtf(d3 + EPSF) - 0.5f, 0.f); atomicAdd(&vloc[k3], h * h);
    __syncthreads();
    if (tid < KLAB) atomicAdd(&g_vsum[b * KLAB + tid], vloc[tid]);
}

// Epilogue: all-batch mu staged once in LDS; wave-shuffle reductions; scalar out.
__global__ __launch_bounds__(256) void k_final(
    const float* __restrict__ g_sums, const float* __restrict__ g_cnt,
    const float* __restrict__ g_vsum, float* __restrict__ out)
{
    __shared__ float mu8[BATCH][FDIM][KLAB];   // 32 KB
    __shared__ float cnt8[BATCH][KLAB];
    __shared__ float tot[BATCH];
    const int tid = threadIdx.x;
    const int l = tid & 63, w = tid >> 6;

    for (int i = tid; i < BATCH * FDIM * KLAB; i += 256) {
        const int bb = i >> 10, k = i & 31;
        (&mu8[0][0][0])[i] = g_sums[i] / fmaxf(g_cnt[bb * KLAB + k], 1.f);
    }
    (&cnt8[0][0])[tid] = g_cnt[tid];           // 256 == BATCH*KLAB
    __syncthreads();

    for (int half = 0; half < 2; ++half) {
        const int bb = w + half * 4;           // wave w handles batches w, w+4
        float pres = 0.f, varp = 0.f, regp = 0.f, distp = 0.f;
        if (l < KLAB && cnt8[bb][l] > 0.f) {
            pres = 1.f;
            varp = g_vsum[bb * KLAB + l] / fmaxf(cnt8[bb][l], 1.f);
            float s = 0.f;
            for (int f = 0; f < FDIM; ++f) { float m = mu8[bb][f][l]; s += m * m; }
            regp = sqrtf(s + EPSF);
        }
        for (int p = l; p < KLAB * KLAB; p += 64) {
            const int i = p >> 5, j = p & 31;
            if (i < j && cnt8[bb][i] > 0.f && cnt8[bb][j] > 0.f) {
                float s = 0.f;
                for (int f = 0; f < FDIM; ++f) {
                    float d = mu8[bb][f][i] - mu8[bb][f][j]; s += d * d;
                }
                const float dist = sqrtf(s + EPSF);
                const float hg = fmaxf(1.5f - dist, 0.f);
                distp += hg * hg;
            }
        }
        for (int m = 32; m > 0; m >>= 1) {     // 64-lane butterfly
            pres  += __shfl_xor(pres,  m, 64);
            varp  += __shfl_xor(varp,  m, 64);
            regp  += __shfl_xor(regp,  m, 64);
            distp += __shfl_xor(distp, m, 64);
        }
        if (l == 0) {
            const float C = pres;
            const float var_b = (C > 0.f) ? varp / fmaxf(C, 1.f) : 0.f;
            const float dis_b = (C > 2.f) ? distp / fmaxf(C * (C - 1.f), 1.f) : 0.f;
            const float reg_b = (C > 1.f) ? regp : 0.f;
            tot[bb] = var_b + dis_b + 0.001f * reg_b;
        }
    }
    __syncthreads();
    if (tid == 0) {
        float t = 0.f;
        for (int bb = 0; bb < BATCH; ++bb) t += tot[bb];
        out[0] = t;
    }
}

extern "C" void kernel_launch(void* const* d_in, const int* in_sizes, int n_in,
                              void* d_out, int out_size, void* d_ws, size_t ws_size,
                              hipStream_t stream) {
    const float* x = (const float*)d_in[0];
    const int* lab = (const int*)d_in[1];
    float* out = (float*)d_out;

    // ws: xbf [B][F][N] bf16 (128 MiB) | sums [B][F][K] | counts [B][K] | vsums [B][K]
    const size_t XBF_BYTES = (size_t)BATCH * FDIM * NPIX * 2;
    short* xbf    = (short*)d_ws;
    float* g_sums = (float*)((char*)d_ws + XBF_BYTES);
    float* g_cnt  = g_sums + (size_t)BATCH * FDIM * KLAB;
    float* g_vsum = g_cnt + (size_t)BATCH * KLAB;
    hipMemsetAsync(g_sums, 0, (size_t)(BATCH * FDIM * KLAB + 2 * BATCH * KLAB) * 4, stream);

    dim3 grid1(64, BATCH);     // 512 blocks x 512 thr = 2 blocks/CU, 16 waves/CU
    k_msums<<<grid1, 512, 0, stream>>>(x, lab, g_sums, g_cnt, xbf);
    dim3 grid2(256, BATCH);    // 1024 px/block, 4 px/thread, 8 blocks/CU
    k_var<<<grid2, 256, 0, stream>>>(xbf, lab, g_sums, g_cnt, g_vsum);
    k_final<<<1, 256, 0, stream>>>(g_sums, g_cnt, g_vsum, out);
}